// Round 2
// baseline (430.187 us; speedup 1.0000x reference)
//
#include <hip/hip_runtime.h>
#include <hip/hip_bf16.h>

typedef __attribute__((ext_vector_type(8))) short short8;
typedef __attribute__((ext_vector_type(4))) float floatx4;

#define LDK 136   // LDS row length in bf16 elems (16B-aligned rows; swizzle kills conflicts)

__device__ __forceinline__ unsigned short f2bf(float x) {
    unsigned u = __builtin_bit_cast(unsigned, x);
    return (unsigned short)((u + 0x7fffu + ((u >> 16) & 1u)) >> 16);
}

// Pass1 (ACCUM=false): block = (b, r). s0 = 128*256, s1 = 256.
//   out[b,r,c,d] = sum_k softmax_k(atten_x[b,r,c,k] + g(c,k)) * value[b,r,k,d]
// Pass2 (ACCUM=true):  block = (b, c). s0 = 256, s1 = 128*256.
//   out[b,r,c,d] += sum_k softmax_k(atten_y[b,c,r,k] + g(r,k)) * value[b,k,c,d]
template <bool ACCUM>
__global__ __launch_bounds__(512, 4) void gtrans(
    const float* __restrict__ atten, const float* __restrict__ value,
    float* __restrict__ out, const float* __restrict__ shiftp,
    const float* __restrict__ biasp, int s0, int s1)
{
    __shared__ short Buf[128 * LDK];   // 34816 B: V^T only (P never touches LDS)

    const int bi   = blockIdx.x;
    const int b    = bi >> 7;
    const int i    = bi & 127;
    const int tid  = threadIdx.x;
    const int lane = tid & 63;
    const int w    = tid >> 6;

    const float shift = shiftp[0];
    const float bias  = biasp[0];

    const float* abase = atten + (size_t)bi * (128 * 128);
    const float* vbase = value + (size_t)b * (128 * 128 * 256) + (size_t)i * s0;
    float*       obase = out   + (size_t)b * (128 * 128 * 256) + (size_t)i * s0;

    const int nl  = w * 16 + (lane & 15);   // this lane's P row (MFMA B-operand n)
    const int kq  = (lane >> 4) * 8;        // k-chunk offset within each 32-block
    const int kvb = w * 16 + 8 * (lane >> 5); // V staging: k-row base
    const int dvb = 4 * (lane & 31);          // V staging: local d base

    // ---- 1: A loads directly in B-fragment layout (lane owns 4x8 consecutive k)
    floatx4 av[8];
    {
        const float* arow = abase + nl * 128 + kq;
#pragma unroll
        for (int ks = 0; ks < 4; ++ks) {
            av[2 * ks]     = *(const floatx4*)(arow + ks * 32);
            av[2 * ks + 1] = *(const floatx4*)(arow + ks * 32 + 4);
        }
    }
    // ---- 2: V half0 loads (fully coalesced 1KiB/instr; lane gets 4d x 8k tile)
    floatx4 vv[8];
#pragma unroll
    for (int t = 0; t < 8; ++t)
        vv[t] = *(const floatx4*)(vbase + (size_t)(kvb + t) * s1 + dvb);

    // ---- 3: softmax in registers; only 4 shuffles total per lane
    short8 bfrag[4];
    {
        float m = -1e30f;
#pragma unroll
        for (int ks = 0; ks < 4; ++ks)
#pragma unroll
            for (int h = 0; h < 2; ++h)
#pragma unroll
                for (int e = 0; e < 4; ++e) {
                    float kf = (float)(ks * 32 + kq + h * 4 + e);
                    float d  = kf - (float)nl;
                    float v  = av[2 * ks + h][e] - (shift * d * d + bias);
                    av[2 * ks + h][e] = v;
                    m = fmaxf(m, v);
                }
        m = fmaxf(m, __shfl_xor(m, 16, 64));
        m = fmaxf(m, __shfl_xor(m, 32, 64));
        float s = 0.0f;
#pragma unroll
        for (int t = 0; t < 8; ++t)
#pragma unroll
            for (int e = 0; e < 4; ++e) {
                float ex = __expf(av[t][e] - m);
                av[t][e] = ex;
                s += ex;
            }
        s += __shfl_xor(s, 16, 64);
        s += __shfl_xor(s, 32, 64);
        float r = 1.0f / s;
#pragma unroll
        for (int ks = 0; ks < 4; ++ks)
#pragma unroll
            for (int h = 0; h < 2; ++h)
#pragma unroll
                for (int e = 0; e < 4; ++e)
                    bfrag[ks][h * 4 + e] = (short)f2bf(av[2 * ks + h][e] * r);
    }

    // ---- 4: stage V^T half0: 4 b128 writes/lane, XOR-swizzled (conflict-free)
    auto stageV = [&](const floatx4* vp) {
#pragma unroll
        for (int j = 0; j < 4; ++j) {
            int row = dvb + j;
            int cb  = (kvb >> 3) ^ ((row >> 2) & 15);
            short8 p;
#pragma unroll
            for (int t = 0; t < 8; ++t) p[t] = (short)f2bf(vp[t][j]);
            *(short8*)(&Buf[row * LDK + cb * 8]) = p;
        }
    };
    stageV(vv);
    __syncthreads();

    // ---- 6: V half1 loads in flight during half0 MFMA
    floatx4 vu[8];
#pragma unroll
    for (int t = 0; t < 8; ++t)
        vu[t] = *(const floatx4*)(vbase + (size_t)(kvb + t) * s1 + 128 + dvb);

    // ---- 7: MFMA half0 — D^T[m=d][n=c], A from swizzled V^T, B from registers
    const int am = lane & 15;
    floatx4 acc[8];
#pragma unroll
    for (int t = 0; t < 8; ++t) acc[t] = (floatx4)0.0f;
#pragma unroll
    for (int ks = 0; ks < 4; ++ks) {
#pragma unroll
        for (int t = 0; t < 8; ++t) {
            int row = t * 16 + am;
            int cb  = (ks * 4 + (lane >> 4)) ^ ((row >> 2) & 15);
            short8 af = *(const short8*)(&Buf[row * LDK + cb * 8]);
            acc[t] = __builtin_amdgcn_mfma_f32_16x16x32_bf16(af, bfrag[ks], acc[t], 0, 0, 0);
        }
    }
    __syncthreads();
    // ---- 9: stage V^T half1 (before epilogue stores, so barrier has no vmcnt drain)
    stageV(vu);
    __syncthreads();

    // ---- 11: epilogue half0 (float4, 64B/row per instr)
    float* orow = obase + (size_t)nl * s1 + (lane >> 4) * 4;
#pragma unroll
    for (int t = 0; t < 8; ++t) {
        float* p = orow + t * 16;
        floatx4 res = acc[t];
        if (ACCUM) res = res + *(const floatx4*)p;
        *(floatx4*)p = res;
    }

    // ---- 12: MFMA half1
#pragma unroll
    for (int t = 0; t < 8; ++t) acc[t] = (floatx4)0.0f;
#pragma unroll
    for (int ks = 0; ks < 4; ++ks) {
#pragma unroll
        for (int t = 0; t < 8; ++t) {
            int row = t * 16 + am;
            int cb  = (ks * 4 + (lane >> 4)) ^ ((row >> 2) & 15);
            short8 af = *(const short8*)(&Buf[row * LDK + cb * 8]);
            acc[t] = __builtin_amdgcn_mfma_f32_16x16x32_bf16(af, bfrag[ks], acc[t], 0, 0, 0);
        }
    }
    // ---- 13: epilogue half1
#pragma unroll
    for (int t = 0; t < 8; ++t) {
        float* p = orow + 128 + t * 16;
        floatx4 res = acc[t];
        if (ACCUM) res = res + *(const floatx4*)p;
        *(floatx4*)p = res;
    }
}

extern "C" void kernel_launch(void* const* d_in, const int* in_sizes, int n_in,
                              void* d_out, int out_size, void* d_ws, size_t ws_size,
                              hipStream_t stream) {
    const float* atten_x = (const float*)d_in[1];
    const float* atten_y = (const float*)d_in[2];
    const float* value   = (const float*)d_in[3];
    const float* shiftp  = (const float*)d_in[4];
    const float* biasp   = (const float*)d_in[5];
    float* out = (float*)d_out;

    dim3 grid(1024), block(512);
    gtrans<false><<<grid, block, 0, stream>>>(atten_x, value, out, shiftp, biasp,
                                              128 * 256, 256);
    gtrans<true><<<grid, block, 0, stream>>>(atten_y, value, out, shiftp, biasp,
                                             256, 128 * 256);
}